// Round 12
// baseline (14286.629 us; speedup 1.0000x reference)
//
#include <hip/hip_runtime.h>
#include <cstddef>
#include <cstdint>

#define B_    128
#define S_    52
#define D_    1024
#define H_    16
#define L_    8
#define DFF_  4096
#define DK_   64
#define T_    (B_*S_)
#define EPS_  1e-5f
#define SCALE_ 0.125f

typedef unsigned short ushortx4 __attribute__((ext_vector_type(4)));
typedef unsigned short ushortx8 __attribute__((ext_vector_type(8)));
typedef short  bf16x8 __attribute__((ext_vector_type(8)));
typedef float  f32x4  __attribute__((ext_vector_type(4)));

__device__ __forceinline__ unsigned short f2b(float f) {
  unsigned int u = __builtin_bit_cast(unsigned int, f);
  u = u + 0x7fffu + ((u >> 16) & 1u);
  return (unsigned short)(u >> 16);
}
__device__ __forceinline__ float b2f(unsigned short b) {
  unsigned int u = ((unsigned int)b) << 16;
  return __builtin_bit_cast(float, u);
}
__device__ __forceinline__ void gload16(const void* g, void* l) {
  __builtin_amdgcn_global_load_lds((const __attribute__((address_space(1))) unsigned int*)g,
      (__attribute__((address_space(3))) unsigned int*)l, 16, 0, 0);
}

// ---------------------------------------------------------------------------
// Embedding + BN partial stats
// ---------------------------------------------------------------------------
__global__ __launch_bounds__(256) void k_embed(const int* __restrict__ x,
    const float* __restrict__ aemb, const float* __restrict__ sept,
    float* __restrict__ h, float* __restrict__ part, int* __restrict__ mask)
{
  int row = blockIdx.x;
  int b = row / S_;
  int s = row - b * S_;
  const int* xr = x + (size_t)row * 3;
  int x0 = xr[0], x1 = xr[1], x2 = xr[2];
  bool issep = (x0 == 100) && (x1 == 0) && (x2 == 2);
  bool ispad = (x0 == 100) && (x1 == 0) && (x2 == 0);
  int t = threadIdx.x;
  if (t == 0) mask[row] = ispad ? 0 : 1;
  const float* src = issep ? sept : (aemb + (size_t)x2 * D_);
  size_t base = (size_t)row * D_;
  float4 v = *reinterpret_cast<const float4*>(src + t * 4);
  *reinterpret_cast<float4*>(h + base + t * 4) = v;
  float s1 = v.x + v.y + v.z + v.w;
  float s2 = v.x * v.x + v.y * v.y + v.z * v.z + v.w * v.w;
#pragma unroll
  for (int off = 32; off; off >>= 1) {
    s1 += __shfl_down(s1, off);
    s2 += __shfl_down(s2, off);
  }
  __shared__ float red[8];
  int lane = t & 63, wid = t >> 6;
  if (lane == 0) { red[wid] = s1; red[4 + wid] = s2; }
  __syncthreads();
  if (t == 0) {
    part[(size_t)s * B_ + b]        = red[0] + red[1] + red[2] + red[3];
    part[(size_t)(S_ + s) * B_ + b] = red[4] + red[5] + red[6] + red[7];
  }
}

__global__ __launch_bounds__(128) void k_bn_reduce(const float* __restrict__ part,
                                                   float* __restrict__ stats)
{
  int s = blockIdx.x;
  int t = threadIdx.x;
  float s1 = part[(size_t)s * B_ + t];
  float s2 = part[(size_t)(S_ + s) * B_ + t];
#pragma unroll
  for (int off = 32; off; off >>= 1) {
    s1 += __shfl_down(s1, off);
    s2 += __shfl_down(s2, off);
  }
  __shared__ float red[4];
  int lane = t & 63, wid = t >> 6;
  if (lane == 0) { red[wid] = s1; red[2 + wid] = s2; }
  __syncthreads();
  if (t == 0) {
    stats[s]      = red[0] + red[1];
    stats[S_ + s] = red[2] + red[3];
  }
}

__global__ __launch_bounds__(256) void k_bn_apply(float* __restrict__ h,
    const float* __restrict__ stats, const float* __restrict__ g,
    const float* __restrict__ bb, unsigned short* __restrict__ hb)
{
  int row = blockIdx.x;
  int s = row % S_;
  const float cnt = (float)(B_ * D_);
  float mu  = stats[s] / cnt;
  float var = stats[S_ + s] / cnt - mu * mu;
  float sc  = rsqrtf(var + EPS_) * g[s];
  float off = bb[s] - mu * sc;
  size_t base = (size_t)row * D_;
  int t = threadIdx.x;
  float4 v = *reinterpret_cast<const float4*>(h + base + t * 4);
  v.x = v.x * sc + off; v.y = v.y * sc + off;
  v.z = v.z * sc + off; v.w = v.w * sc + off;
  *reinterpret_cast<float4*>(h + base + t * 4) = v;
  ushortx4 o = { f2b(v.x), f2b(v.y), f2b(v.z), f2b(v.w) };
  *reinterpret_cast<ushortx4*>(hb + base + t * 4) = o;
}

// divide-free vectorized weight conversion: blockIdx.y = segment, .z = layer
__global__ __launch_bounds__(256) void k_wconv6(
    const float* __restrict__ Wq, const float* __restrict__ Wk,
    const float* __restrict__ Wv, const float* __restrict__ Wo,
    const float* __restrict__ W1, const float* __restrict__ W2,
    unsigned short* __restrict__ out)
{
  const size_t DD = (size_t)D_ * D_, DF = (size_t)DFF_ * D_;
  const size_t WPL = 4 * DD + 2 * DF;
  int s = blockIdx.y, l = blockIdx.z;
  const float* src; size_t segsz, dstoff;
  switch (s) {
    case 0:  src = Wq + (size_t)l * DD; segsz = DD; dstoff = 0; break;
    case 1:  src = Wk + (size_t)l * DD; segsz = DD; dstoff = DD; break;
    case 2:  src = Wv + (size_t)l * DD; segsz = DD; dstoff = 2 * DD; break;
    case 3:  src = Wo + (size_t)l * DD; segsz = DD; dstoff = 3 * DD; break;
    case 4:  src = W1 + (size_t)l * DF; segsz = DF; dstoff = 4 * DD; break;
    default: src = W2 + (size_t)l * DF; segsz = DF; dstoff = 4 * DD + DF; break;
  }
  unsigned short* dst = out + (size_t)l * WPL + dstoff;
  size_t stride = (size_t)gridDim.x * 256 * 8;
  for (size_t i = ((size_t)blockIdx.x * 256 + threadIdx.x) * 8; i < segsz; i += stride) {
    float4 v0 = *reinterpret_cast<const float4*>(src + i);
    float4 v1 = *reinterpret_cast<const float4*>(src + i + 4);
    ushortx8 o = { f2b(v0.x), f2b(v0.y), f2b(v0.z), f2b(v0.w),
                   f2b(v1.x), f2b(v1.y), f2b(v1.z), f2b(v1.w) };
    *reinterpret_cast<ushortx8*>(dst + i) = o;
  }
}

// concat per-layer qkv biases -> bqkv_all[L][3072]
__global__ __launch_bounds__(256) void k_bcat(const float* __restrict__ bq,
    const float* __restrict__ bk, const float* __restrict__ bv,
    float* __restrict__ out)
{
  int i = blockIdx.x * 256 + threadIdx.x;
  int l = i / 3072, j = i - l * 3072;
  float v = (j < D_) ? bq[l * D_ + j] : (j < 2 * D_) ? bk[l * D_ + j - D_]
                                                     : bv[l * D_ + j - 2 * D_];
  out[i] = v;
}

// ---------------------------------------------------------------------------
// Pipelined bf16 MFMA GEMM: C = A @ Wt^T + bias
// BM=256, BN=128, BK=32, 8 waves (4M x 2N), wave-tile 64x64.
// 2 LDS buffers x 24KB = 48KB -> 3 blocks/CU (kills 2-round tail quantization
// for 624-block QKV; more TLP for all). Depth-1 prefetch: stage t+1 issued one
// full K-step before its vmcnt(0) wait (~2000cyc >> 900cyc HBM latency).
// 64B-row swizzle sigma(row)=(row>>1)&3 on global source AND ds_read
// (measured 0 bank conflicts). 8x8 supertile under XCD swizzle.
// ---------------------------------------------------------------------------
template<int RELU, int OUTBF16>
__global__ __launch_bounds__(512, 6) void k_gemm8(
    const unsigned short* __restrict__ A, const unsigned short* __restrict__ Wt,
    const float* __restrict__ bias, void* __restrict__ C,
    int Mtiles, int Ntiles, int K, int ldc)
{
  __shared__ unsigned short lds[2 * 12288];   // 48 KB
  const int tid = threadIdx.x;
  const int w = tid >> 6, l = tid & 63;

  const int nwg = Mtiles * Ntiles;
  int id = blockIdx.x;
  int swz = (id & 7) * (nwg >> 3) + (id >> 3);
  const int stripe = swz / (Ntiles << 3);
  const int r = swz - stripe * (Ntiles << 3);
  int hg = Mtiles - (stripe << 3); if (hg > 8) hg = 8;
  const int c = r / (hg << 3);
  const int q = r - c * (hg << 3);
  const int bym = (stripe << 3) + (q >> 3);
  const int bxn = (c << 3) + (q & 7);
  const int bm = bym * 256, bn = bxn * 128;

  const int colsw = 16 * ((l & 3) ^ ((l >> 3) & 3));
  const char* gA = (const char*)A + ((size_t)(bm + w * 32 + (l >> 2)) * K) * 2 + colsw;
  const char* gB = (const char*)Wt + ((size_t)(bn + w * 16 + (l >> 2)) * K) * 2 + colsw;
  const size_t r16 = (size_t)16 * K * 2;
  unsigned short* lA = lds + w * 1024;
  unsigned short* lB = lds + 8192 + w * 512;

#define STAGE(tt, bb) do {                          \
    size_t ko_ = (size_t)(tt) * 64;                 \
    unsigned short* la_ = lA + (bb) * 12288;        \
    unsigned short* lb_ = lB + (bb) * 12288;        \
    gload16(gA + ko_,       la_);                   \
    gload16(gA + ko_ + r16, la_ + 512);             \
    gload16(gB + ko_,       lb_);                   \
  } while (0)

  const int fr = l & 15, kg = l >> 4;
  const int wr = w >> 1, wc = w & 1;
  const int xk = 16 * (kg ^ ((fr >> 1) & 3));
  const int aOff = (wr * 64 + fr) * 64 + xk;
  const int bOff = 16384 + (wc * 64 + fr) * 64 + xk;

  f32x4 acc[4][4] = {};
  const int NT = K >> 5;

  STAGE(0, 0);
  int cur = 0;
  for (int t = 0; t < NT; ++t) {
    asm volatile("s_waitcnt vmcnt(0)" ::: "memory");
    __builtin_amdgcn_sched_barrier(0);
    __builtin_amdgcn_s_barrier();
    __builtin_amdgcn_sched_barrier(0);
    if (t + 1 < NT) STAGE(t + 1, cur ^ 1);
    const char* bp = (const char*)lds + cur * 24576;
    bf16x8 af[4], bfv[4];
#pragma unroll
    for (int mf = 0; mf < 4; ++mf)
      af[mf] = *(const bf16x8*)(bp + aOff + mf * 1024);
#pragma unroll
    for (int nf = 0; nf < 4; ++nf)
      bfv[nf] = *(const bf16x8*)(bp + bOff + nf * 1024);
    asm volatile("s_waitcnt lgkmcnt(0)" ::: "memory");
    __builtin_amdgcn_sched_barrier(0);
    __builtin_amdgcn_s_setprio(1);
#pragma unroll
    for (int mf = 0; mf < 4; ++mf)
#pragma unroll
      for (int nf = 0; nf < 4; ++nf)
        acc[mf][nf] = __builtin_amdgcn_mfma_f32_16x16x32_bf16(af[mf], bfv[nf], acc[mf][nf], 0, 0, 0);
    __builtin_amdgcn_s_setprio(0);
    __builtin_amdgcn_sched_barrier(0);
    cur ^= 1;
  }
#undef STAGE

#pragma unroll
  for (int nf = 0; nf < 4; ++nf) {
    int col = bn + wc * 64 + nf * 16 + fr;
    float bv = bias[col];
#pragma unroll
    for (int mf = 0; mf < 4; ++mf) {
      int row0 = bm + wr * 64 + mf * 16 + kg * 4;
#pragma unroll
      for (int j = 0; j < 4; ++j) {
        float v = acc[mf][nf][j] + bv;
        if (RELU) v = fmaxf(v, 0.f);
        if (OUTBF16)
          ((unsigned short*)C)[(size_t)(row0 + j) * ldc + col] = f2b(v);
        else
          ((float*)C)[(size_t)(row0 + j) * ldc + col] = v;
      }
    }
  }
}

// ---------------------------------------------------------------------------
// MFMA sparse attention: one wave per (b, head).
// ---------------------------------------------------------------------------
__global__ __launch_bounds__(64) void k_attn(const unsigned short* __restrict__ qkv,
    const int* __restrict__ mask, unsigned short* __restrict__ ao)
{
  __shared__ float sc[64][68];
  __shared__ unsigned short ph[64][68];
  __shared__ unsigned short plo[64][68];
  __shared__ unsigned short vT[64][68];
  __shared__ float dnm[64];

  int blk = blockIdx.x;
  int b = blk >> 4, hh = blk & 15;
  int l = threadIdx.x;
  int cl = l & 15, kg = l >> 4;
  const unsigned short* base = qkv + (size_t)(b * S_) * 3072 + hh * 64;

  {
    const unsigned short* vp = base + 2048 + l;
#pragma unroll 4
    for (int k = 0; k < S_; ++k)
      vT[l][k] = vp[(size_t)k * 3072];
#pragma unroll
    for (int k = S_; k < 64; ++k) vT[l][k] = 0;
  }

  bf16x8 qa[4][2], kb[4][2];
#pragma unroll
  for (int mi = 0; mi < 4; ++mi) {
    int row = mi * 16 + cl;
    bool ok = (row < S_);
    const unsigned short* qp = base + (size_t)row * 3072 + kg * 8;
#pragma unroll
    for (int ks = 0; ks < 2; ++ks) {
      bf16x8 z = {};
      qa[mi][ks] = ok ? *reinterpret_cast<const bf16x8*>(qp + ks * 32) : z;
      kb[mi][ks] = ok ? *reinterpret_cast<const bf16x8*>(qp + 1024 + ks * 32) : z;
    }
  }

  f32x4 acc[4][4] = {};
#pragma unroll
  for (int ks = 0; ks < 2; ++ks)
#pragma unroll
    for (int mi = 0; mi < 4; ++mi)
#pragma unroll
      for (int ci = 0; ci < 4; ++ci)
        acc[mi][ci] = __builtin_amdgcn_mfma_f32_16x16x32_bf16(qa[mi][ks], kb[ci][ks], acc[mi][ci], 0, 0, 0);

  int vld[4];
#pragma unroll
  for (int ci = 0; ci < 4; ++ci) {
    int col = ci * 16 + cl;
    vld[ci] = (col < S_) ? mask[b * S_ + col] : 0;
  }
#pragma unroll
  for (int mi = 0; mi < 4; ++mi)
#pragma unroll
    for (int ci = 0; ci < 4; ++ci)
#pragma unroll
      for (int j = 0; j < 4; ++j)
        sc[mi * 16 + kg * 4 + j][ci * 16 + cl] = vld[ci] ? acc[mi][ci][j] * SCALE_ : -1e9f;

  __syncthreads();

  if (l < S_) {
    float v0 = -3e38f, v1 = -3e38f, v2 = -3e38f, v3 = -3e38f, v4 = -3e38f;
    const float4* rp = reinterpret_cast<const float4*>(&sc[l][0]);
#pragma unroll
    for (int c4 = 0; c4 < 13; ++c4) {
      float4 x = rp[c4];
      float xs[4] = { x.x, x.y, x.z, x.w };
#pragma unroll
      for (int u = 0; u < 4; ++u) {
        float xv = xs[u];
        if      (xv > v0) { v4 = v3; v3 = v2; v2 = v1; v1 = v0; v0 = xv; }
        else if (xv > v1) { v4 = v3; v3 = v2; v2 = v1; v1 = xv; }
        else if (xv > v2) { v4 = v3; v3 = v2; v2 = xv; }
        else if (xv > v3) { v4 = v3; v3 = xv; }
        else if (xv > v4) { v4 = xv; }
      }
    }
    float thr = v4;
    float m = fmaxf(v0, 0.f);
    float denom = 0.f;
    for (int c = 0; c < S_; ++c) {
      float xv = sc[l][c];
      float sp = (xv >= thr) ? xv : 0.f;
      float e = __expf(sp - m);
      denom += e;
      unsigned short hi = f2b(e);
      ph[l][c] = hi;
      plo[l][c] = f2b(e - b2f(hi));
    }
#pragma unroll
    for (int c = S_; c < 64; ++c) { ph[l][c] = 0; plo[l][c] = 0; }
    dnm[l] = 1.f / denom;
  }
  __syncthreads();

  f32x4 o[4][4] = {};
#pragma unroll
  for (int ks = 0; ks < 2; ++ks) {
    bf16x8 vf[4];
#pragma unroll
    for (int di = 0; di < 4; ++di)
      vf[di] = *reinterpret_cast<const bf16x8*>(&vT[di * 16 + cl][ks * 32 + kg * 8]);
#pragma unroll
    for (int mi = 0; mi < 4; ++mi) {
      bf16x8 ahi = *reinterpret_cast<const bf16x8*>(&ph[mi * 16 + cl][ks * 32 + kg * 8]);
      bf16x8 alo = *reinterpret_cast<const bf16x8*>(&plo[mi * 16 + cl][ks * 32 + kg * 8]);
#pragma unroll
      for (int di = 0; di < 4; ++di) {
        o[mi][di] = __builtin_amdgcn_mfma_f32_16x16x32_bf16(ahi, vf[di], o[mi][di], 0, 0, 0);
        o[mi][di] = __builtin_amdgcn_mfma_f32_16x16x32_bf16(alo, vf[di], o[mi][di], 0, 0, 0);
      }
    }
  }

#pragma unroll
  for (int mi = 0; mi < 4; ++mi) {
    int row = mi * 16 + kg * 4;
    if (row < S_) {
#pragma unroll
      for (int j = 0; j < 4; ++j) {
        int r = row + j;
        float inv = dnm[r];
        unsigned short* aop = ao + (size_t)(b * S_ + r) * D_ + hh * DK_;
#pragma unroll
        for (int di = 0; di < 4; ++di)
          aop[di * 16 + cl] = f2b(o[mi][di][j] * inv);
      }
    }
  }
}

// ---------------------------------------------------------------------------
// h = LayerNorm(h + r); r is bf16; writes fp32 h and bf16 hb. Vectorized.
// ---------------------------------------------------------------------------
__global__ __launch_bounds__(256) void k_add_ln(float* __restrict__ h,
    const unsigned short* __restrict__ r, const float* __restrict__ g,
    const float* __restrict__ bb, unsigned short* __restrict__ hb)
{
  int row = blockIdx.x;
  size_t base = (size_t)row * D_;
  int t = threadIdx.x;
  float4 hv = *reinterpret_cast<const float4*>(h + base + t * 4);
  ushortx4 rv = *reinterpret_cast<const ushortx4*>(r + base + t * 4);
  float xs[4] = { hv.x + b2f(rv[0]), hv.y + b2f(rv[1]),
                  hv.z + b2f(rv[2]), hv.w + b2f(rv[3]) };
  float s1 = xs[0] + xs[1] + xs[2] + xs[3];
  float s2 = xs[0] * xs[0] + xs[1] * xs[1] + xs[2] * xs[2] + xs[3] * xs[3];
#pragma unroll
  for (int off = 32; off; off >>= 1) {
    s1 += __shfl_down(s1, off);
    s2 += __shfl_down(s2, off);
  }
  __shared__ float red[8];
  int lane = t & 63, wid = t >> 6;
  if (lane == 0) { red[wid] = s1; red[4 + wid] = s2; }
  __syncthreads();
  if (t == 0) {
    red[0] = red[0] + red[1] + red[2] + red[3];
    red[4] = red[4] + red[5] + red[6] + red[7];
  }
  __syncthreads();
  float mean = red[0] / (float)D_;
  float var  = red[4] / (float)D_ - mean * mean;
  float inv  = rsqrtf(var + EPS_);
  float4 gv = *reinterpret_cast<const float4*>(g + t * 4);
  float4 bv = *reinterpret_cast<const float4*>(bb + t * 4);
  float4 ov;
  ov.x = (xs[0] - mean) * inv * gv.x + bv.x;
  ov.y = (xs[1] - mean) * inv * gv.y + bv.y;
  ov.z = (xs[2] - mean) * inv * gv.z + bv.z;
  ov.w = (xs[3] - mean) * inv * gv.w + bv.w;
  *reinterpret_cast<float4*>(h + base + t * 4) = ov;
  ushortx4 ob = { f2b(ov.x), f2b(ov.y), f2b(ov.z), f2b(ov.w) };
  *reinterpret_cast<ushortx4*>(hb + base + t * 4) = ob;
}

// ---------------------------------------------------------------------------
__global__ __launch_bounds__(256) void k_final(const float* __restrict__ h,
    const float* __restrict__ Wout, const float* __restrict__ bout,
    float* __restrict__ y)
{
  int b = blockIdx.x;
  const float* hr = h + (size_t)(b * S_ + (S_ - 1)) * D_;
  int t = threadIdx.x;
  float p0 = 0.f, p1 = 0.f, p2 = 0.f;
  for (int d = t; d < D_; d += 256) {
    float xv = hr[d];
    p0 += xv * Wout[d];
    p1 += xv * Wout[D_ + d];
    p2 += xv * Wout[2 * D_ + d];
  }
#pragma unroll
  for (int off = 32; off; off >>= 1) {
    p0 += __shfl_down(p0, off);
    p1 += __shfl_down(p1, off);
    p2 += __shfl_down(p2, off);
  }
  __shared__ float red[12];
  int lane = t & 63, wid = t >> 6;
  if (lane == 0) { red[wid] = p0; red[4 + wid] = p1; red[8 + wid] = p2; }
  __syncthreads();
  if (t == 0) {
    y[b * 3 + 0] = red[0] + red[1] + red[2]  + red[3]  + bout[0];
    y[b * 3 + 1] = red[4] + red[5] + red[6]  + red[7]  + bout[1];
    y[b * 3 + 2] = red[8] + red[9] + red[10] + red[11] + bout[2];
  }
}

// ---------------------------------------------------------------------------
extern "C" void kernel_launch(void* const* d_in, const int* in_sizes, int n_in,
                              void* d_out, int out_size, void* d_ws, size_t ws_size,
                              hipStream_t stream)
{
  const int*   x    = (const int*)d_in[0];
  const float* aemb = (const float*)d_in[1];
  const float* sept = (const float*)d_in[2];
  const float* bng  = (const float*)d_in[3];
  const float* bnb  = (const float*)d_in[4];
  const float* Wq = (const float*)d_in[5];  const float* bq = (const float*)d_in[6];
  const float* Wk = (const float*)d_in[7];  const float* bk = (const float*)d_in[8];
  const float* Wv = (const float*)d_in[9];  const float* bv = (const float*)d_in[10];
  const float* Wo = (const float*)d_in[11]; const float* bo = (const float*)d_in[12];
  const float* W1 = (const float*)d_in[13]; const float* b1 = (const float*)d_in[14];
  const float* W2 = (const float*)d_in[15]; const float* b2 = (const float*)d_in[16];
  const float* ln1g = (const float*)d_in[17]; const float* ln1b = (const float*)d_in[18];
  const float* ln2g = (const float*)d_in[19]; const float* ln2b = (const float*)d_in[20];
  const float* Wout = (const float*)d_in[21]; const float* bout = (const float*)d_in[22];
  float* out = (float*)d_out;

  float* ws = (float*)d_ws;
  const size_t TD = (size_t)T_ * D_;
  const size_t DD = (size_t)D_ * D_;
  const size_t DF = (size_t)DFF_ * D_;
  const size_t WPL = 4 * DD + 2 * DF;                               // ushorts/layer
  float* h   = ws;                                                  // TD f32
  unsigned short* tmpb = (unsigned short*)(ws + TD);                // TD bf16
  unsigned short* hb   = (unsigned short*)(ws + 2 * TD);            // TD bf16
  unsigned short* qkvb = (unsigned short*)(ws + 2 * TD + TD / 2);   // 3TD bf16
  unsigned short* aob  = (unsigned short*)(ws + 4 * TD);            // TD bf16
  unsigned short* ffb  = (unsigned short*)(ws + 4 * TD + TD / 2);   // 4TD bf16
  float* bqkv  = ws + 6 * TD + TD / 2;                              // L*3072 f32
  float* stats = bqkv + L_ * 3072;
  float* part  = stats + 2 * S_;
  int*   mask  = (int*)(part + 2 * S_ * B_);
  size_t usedB = ((char*)(mask + T_) - (char*)ws + 255) & ~(size_t)255;
  unsigned short* wbuf = (unsigned short*)((char*)ws + usedB);
  const int all8 = (ws_size >= usedB + 8 * WPL * sizeof(unsigned short)) ? 1 : 0;

  k_embed<<<T_, 256, 0, stream>>>(x, aemb, sept, h, part, mask);
  k_bn_reduce<<<S_, 128, 0, stream>>>(part, stats);
  k_bn_apply<<<T_, 256, 0, stream>>>(h, stats, bng, bnb, hb);
  k_bcat<<<(L_ * 3072) / 256, 256, 0, stream>>>(bq, bk, bv, bqkv);
  if (all8)
    k_wconv6<<<dim3(128, 6, 8), 256, 0, stream>>>(Wq, Wk, Wv, Wo, W1, W2, wbuf);

  for (int l = 0; l < L_; ++l) {
    unsigned short* wl = all8 ? (wbuf + (size_t)l * WPL) : wbuf;
    if (!all8)
      k_wconv6<<<dim3(128, 6, 1), 256, 0, stream>>>(Wq + l * DD, Wk + l * DD,
          Wv + l * DD, Wo + l * DD, W1 + l * DF, W2 + l * DF, wbuf);
    // QKV: M=6656 (26 Mtiles of 256), N=3072 (24 Ntiles of 128), K=1024
    k_gemm8<0, 1><<<26 * 24, 512, 0, stream>>>(hb, wl, bqkv + l * 3072,
        qkvb, 26, 24, 1024, 3072);
    k_attn<<<B_ * H_, 64, 0, stream>>>(qkvb, mask, aob);
    // O-proj: N=1024 (8 Ntiles), K=1024 -> bf16 tmpb
    k_gemm8<0, 1><<<26 * 8, 512, 0, stream>>>(aob, wl + 3 * DD, bo + l * D_,
        tmpb, 26, 8, 1024, 1024);
    k_add_ln<<<T_, 256, 0, stream>>>(h, tmpb, ln1g + l * D_, ln1b + l * D_, hb);
    // FFN1: N=4096 (32 Ntiles), K=1024, relu
    k_gemm8<1, 1><<<26 * 32, 512, 0, stream>>>(hb, wl + 4 * DD, b1 + l * DFF_,
        ffb, 26, 32, 1024, 4096);
    // FFN2: N=1024 (8 Ntiles), K=4096 -> bf16 tmpb
    k_gemm8<0, 1><<<26 * 8, 512, 0, stream>>>(ffb, wl + 4 * DD + DF, b2 + l * D_,
        tmpb, 26, 8, 4096, 1024);
    k_add_ln<<<T_, 256, 0, stream>>>(h, tmpb, ln2g + l * D_, ln2b + l * D_, hb);
  }
  k_final<<<B_, 256, 0, stream>>>(h, Wout, bout, out);
}

// Round 13
// 2665.212 us; speedup vs baseline: 5.3604x; 5.3604x over previous
//
#include <hip/hip_runtime.h>
#include <cstddef>
#include <cstdint>

#define B_    128
#define S_    52
#define D_    1024
#define H_    16
#define L_    8
#define DFF_  4096
#define DK_   64
#define T_    (B_*S_)
#define EPS_  1e-5f
#define SCALE_ 0.125f

typedef unsigned short ushortx4 __attribute__((ext_vector_type(4)));
typedef unsigned short ushortx8 __attribute__((ext_vector_type(8)));
typedef short  bf16x8 __attribute__((ext_vector_type(8)));
typedef float  f32x4  __attribute__((ext_vector_type(4)));

__device__ __forceinline__ unsigned short f2b(float f) {
  unsigned int u = __builtin_bit_cast(unsigned int, f);
  u = u + 0x7fffu + ((u >> 16) & 1u);
  return (unsigned short)(u >> 16);
}
__device__ __forceinline__ float b2f(unsigned short b) {
  unsigned int u = ((unsigned int)b) << 16;
  return __builtin_bit_cast(float, u);
}
__device__ __forceinline__ void gload16(const void* g, void* l) {
  __builtin_amdgcn_global_load_lds((const __attribute__((address_space(1))) unsigned int*)g,
      (__attribute__((address_space(3))) unsigned int*)l, 16, 0, 0);
}

// ---------------------------------------------------------------------------
// Embedding + BN partial stats
// ---------------------------------------------------------------------------
__global__ __launch_bounds__(256) void k_embed(const int* __restrict__ x,
    const float* __restrict__ aemb, const float* __restrict__ sept,
    float* __restrict__ h, float* __restrict__ part, int* __restrict__ mask)
{
  int row = blockIdx.x;
  int b = row / S_;
  int s = row - b * S_;
  const int* xr = x + (size_t)row * 3;
  int x0 = xr[0], x1 = xr[1], x2 = xr[2];
  bool issep = (x0 == 100) && (x1 == 0) && (x2 == 2);
  bool ispad = (x0 == 100) && (x1 == 0) && (x2 == 0);
  int t = threadIdx.x;
  if (t == 0) mask[row] = ispad ? 0 : 1;
  const float* src = issep ? sept : (aemb + (size_t)x2 * D_);
  size_t base = (size_t)row * D_;
  float4 v = *reinterpret_cast<const float4*>(src + t * 4);
  *reinterpret_cast<float4*>(h + base + t * 4) = v;
  float s1 = v.x + v.y + v.z + v.w;
  float s2 = v.x * v.x + v.y * v.y + v.z * v.z + v.w * v.w;
#pragma unroll
  for (int off = 32; off; off >>= 1) {
    s1 += __shfl_down(s1, off);
    s2 += __shfl_down(s2, off);
  }
  __shared__ float red[8];
  int lane = t & 63, wid = t >> 6;
  if (lane == 0) { red[wid] = s1; red[4 + wid] = s2; }
  __syncthreads();
  if (t == 0) {
    part[(size_t)s * B_ + b]        = red[0] + red[1] + red[2] + red[3];
    part[(size_t)(S_ + s) * B_ + b] = red[4] + red[5] + red[6] + red[7];
  }
}

__global__ __launch_bounds__(128) void k_bn_reduce(const float* __restrict__ part,
                                                   float* __restrict__ stats)
{
  int s = blockIdx.x;
  int t = threadIdx.x;
  float s1 = part[(size_t)s * B_ + t];
  float s2 = part[(size_t)(S_ + s) * B_ + t];
#pragma unroll
  for (int off = 32; off; off >>= 1) {
    s1 += __shfl_down(s1, off);
    s2 += __shfl_down(s2, off);
  }
  __shared__ float red[4];
  int lane = t & 63, wid = t >> 6;
  if (lane == 0) { red[wid] = s1; red[2 + wid] = s2; }
  __syncthreads();
  if (t == 0) {
    stats[s]      = red[0] + red[1];
    stats[S_ + s] = red[2] + red[3];
  }
}

__global__ __launch_bounds__(256) void k_bn_apply(float* __restrict__ h,
    const float* __restrict__ stats, const float* __restrict__ g,
    const float* __restrict__ bb, unsigned short* __restrict__ hb)
{
  int row = blockIdx.x;
  int s = row % S_;
  const float cnt = (float)(B_ * D_);
  float mu  = stats[s] / cnt;
  float var = stats[S_ + s] / cnt - mu * mu;
  float sc  = rsqrtf(var + EPS_) * g[s];
  float off = bb[s] - mu * sc;
  size_t base = (size_t)row * D_;
  int t = threadIdx.x;
  float4 v = *reinterpret_cast<const float4*>(h + base + t * 4);
  v.x = v.x * sc + off; v.y = v.y * sc + off;
  v.z = v.z * sc + off; v.w = v.w * sc + off;
  *reinterpret_cast<float4*>(h + base + t * 4) = v;
  ushortx4 o = { f2b(v.x), f2b(v.y), f2b(v.z), f2b(v.w) };
  *reinterpret_cast<ushortx4*>(hb + base + t * 4) = o;
}

// divide-free vectorized weight conversion: blockIdx.y = segment, .z = layer
__global__ __launch_bounds__(256) void k_wconv6(
    const float* __restrict__ Wq, const float* __restrict__ Wk,
    const float* __restrict__ Wv, const float* __restrict__ Wo,
    const float* __restrict__ W1, const float* __restrict__ W2,
    unsigned short* __restrict__ out)
{
  const size_t DD = (size_t)D_ * D_, DF = (size_t)DFF_ * D_;
  const size_t WPL = 4 * DD + 2 * DF;
  int s = blockIdx.y, l = blockIdx.z;
  const float* src; size_t segsz, dstoff;
  switch (s) {
    case 0:  src = Wq + (size_t)l * DD; segsz = DD; dstoff = 0; break;
    case 1:  src = Wk + (size_t)l * DD; segsz = DD; dstoff = DD; break;
    case 2:  src = Wv + (size_t)l * DD; segsz = DD; dstoff = 2 * DD; break;
    case 3:  src = Wo + (size_t)l * DD; segsz = DD; dstoff = 3 * DD; break;
    case 4:  src = W1 + (size_t)l * DF; segsz = DF; dstoff = 4 * DD; break;
    default: src = W2 + (size_t)l * DF; segsz = DF; dstoff = 4 * DD + DF; break;
  }
  unsigned short* dst = out + (size_t)l * WPL + dstoff;
  size_t stride = (size_t)gridDim.x * 256 * 8;
  for (size_t i = ((size_t)blockIdx.x * 256 + threadIdx.x) * 8; i < segsz; i += stride) {
    float4 v0 = *reinterpret_cast<const float4*>(src + i);
    float4 v1 = *reinterpret_cast<const float4*>(src + i + 4);
    ushortx8 o = { f2b(v0.x), f2b(v0.y), f2b(v0.z), f2b(v0.w),
                   f2b(v1.x), f2b(v1.y), f2b(v1.z), f2b(v1.w) };
    *reinterpret_cast<ushortx8*>(dst + i) = o;
  }
}

// concat per-layer qkv biases -> bqkv_all[L][3072]
__global__ __launch_bounds__(256) void k_bcat(const float* __restrict__ bq,
    const float* __restrict__ bk, const float* __restrict__ bv,
    float* __restrict__ out)
{
  int i = blockIdx.x * 256 + threadIdx.x;
  int l = i / 3072, j = i - l * 3072;
  float v = (j < D_) ? bq[l * D_ + j] : (j < 2 * D_) ? bk[l * D_ + j - D_]
                                                     : bv[l * D_ + j - 2 * D_];
  out[i] = v;
}

// ---------------------------------------------------------------------------
// Pipelined bf16 MFMA GEMM: C = A @ Wt^T + bias
// BM=256, BN=128, BK=32, 8 waves (4M x 2N), wave-tile 64x64.
// 2 LDS buffers x 24KB = 48KB. Occupancy is LDS-limited at 3 blocks/CU
// (VGPR ~56 is not binding). NOTE: do NOT raise the 2nd __launch_bounds__
// arg above 4 -- R12 showed (512,6) caps the register allocator (VGPR=40),
// spills acc[4][4] to scratch (1.5 GB writes/dispatch, MfmaUtil 3.5%).
// Depth-1 prefetch: stage t+1 issued right after the barrier, waited at
// iter t+1's vmcnt(0) -- one full compute phase of latency cover.
// 64B-row swizzle sigma(row)=(row>>1)&3 on global source AND ds_read
// (measured 0 bank conflicts). 8x8 supertile under XCD swizzle.
// ---------------------------------------------------------------------------
template<int RELU, int OUTBF16>
__global__ __launch_bounds__(512, 4) void k_gemm8(
    const unsigned short* __restrict__ A, const unsigned short* __restrict__ Wt,
    const float* __restrict__ bias, void* __restrict__ C,
    int Mtiles, int Ntiles, int K, int ldc)
{
  __shared__ unsigned short lds[2 * 12288];   // 48 KB
  const int tid = threadIdx.x;
  const int w = tid >> 6, l = tid & 63;

  const int nwg = Mtiles * Ntiles;
  int id = blockIdx.x;
  int swz = (id & 7) * (nwg >> 3) + (id >> 3);
  const int stripe = swz / (Ntiles << 3);
  const int r = swz - stripe * (Ntiles << 3);
  int hg = Mtiles - (stripe << 3); if (hg > 8) hg = 8;
  const int c = r / (hg << 3);
  const int q = r - c * (hg << 3);
  const int bym = (stripe << 3) + (q >> 3);
  const int bxn = (c << 3) + (q & 7);
  const int bm = bym * 256, bn = bxn * 128;

  const int colsw = 16 * ((l & 3) ^ ((l >> 3) & 3));
  const char* gA = (const char*)A + ((size_t)(bm + w * 32 + (l >> 2)) * K) * 2 + colsw;
  const char* gB = (const char*)Wt + ((size_t)(bn + w * 16 + (l >> 2)) * K) * 2 + colsw;
  const size_t r16 = (size_t)16 * K * 2;
  unsigned short* lA = lds + w * 1024;
  unsigned short* lB = lds + 8192 + w * 512;

#define STAGE(tt, bb) do {                          \
    size_t ko_ = (size_t)(tt) * 64;                 \
    unsigned short* la_ = lA + (bb) * 12288;        \
    unsigned short* lb_ = lB + (bb) * 12288;        \
    gload16(gA + ko_,       la_);                   \
    gload16(gA + ko_ + r16, la_ + 512);             \
    gload16(gB + ko_,       lb_);                   \
  } while (0)

  const int fr = l & 15, kg = l >> 4;
  const int wr = w >> 1, wc = w & 1;
  const int xk = 16 * (kg ^ ((fr >> 1) & 3));
  const int aOff = (wr * 64 + fr) * 64 + xk;
  const int bOff = 16384 + (wc * 64 + fr) * 64 + xk;

  f32x4 acc[4][4] = {};
  const int NT = K >> 5;

  STAGE(0, 0);
  int cur = 0;
  for (int t = 0; t < NT; ++t) {
    asm volatile("s_waitcnt vmcnt(0)" ::: "memory");
    __builtin_amdgcn_sched_barrier(0);
    __builtin_amdgcn_s_barrier();
    __builtin_amdgcn_sched_barrier(0);
    if (t + 1 < NT) STAGE(t + 1, cur ^ 1);
    const char* bp = (const char*)lds + cur * 24576;
    bf16x8 af[4], bfv[4];
#pragma unroll
    for (int mf = 0; mf < 4; ++mf)
      af[mf] = *(const bf16x8*)(bp + aOff + mf * 1024);
#pragma unroll
    for (int nf = 0; nf < 4; ++nf)
      bfv[nf] = *(const bf16x8*)(bp + bOff + nf * 1024);
    asm volatile("s_waitcnt lgkmcnt(0)" ::: "memory");
    __builtin_amdgcn_sched_barrier(0);
    __builtin_amdgcn_s_setprio(1);
#pragma unroll
    for (int mf = 0; mf < 4; ++mf)
#pragma unroll
      for (int nf = 0; nf < 4; ++nf)
        acc[mf][nf] = __builtin_amdgcn_mfma_f32_16x16x32_bf16(af[mf], bfv[nf], acc[mf][nf], 0, 0, 0);
    __builtin_amdgcn_s_setprio(0);
    __builtin_amdgcn_sched_barrier(0);
    cur ^= 1;
  }
#undef STAGE

#pragma unroll
  for (int nf = 0; nf < 4; ++nf) {
    int col = bn + wc * 64 + nf * 16 + fr;
    float bv = bias[col];
#pragma unroll
    for (int mf = 0; mf < 4; ++mf) {
      int row0 = bm + wr * 64 + mf * 16 + kg * 4;
#pragma unroll
      for (int j = 0; j < 4; ++j) {
        float v = acc[mf][nf][j] + bv;
        if (RELU) v = fmaxf(v, 0.f);
        if (OUTBF16)
          ((unsigned short*)C)[(size_t)(row0 + j) * ldc + col] = f2b(v);
        else
          ((float*)C)[(size_t)(row0 + j) * ldc + col] = v;
      }
    }
  }
}

// ---------------------------------------------------------------------------
// MFMA sparse attention: one wave per (b, head).
// ---------------------------------------------------------------------------
__global__ __launch_bounds__(64) void k_attn(const unsigned short* __restrict__ qkv,
    const int* __restrict__ mask, unsigned short* __restrict__ ao)
{
  __shared__ float sc[64][68];
  __shared__ unsigned short ph[64][68];
  __shared__ unsigned short plo[64][68];
  __shared__ unsigned short vT[64][68];
  __shared__ float dnm[64];

  int blk = blockIdx.x;
  int b = blk >> 4, hh = blk & 15;
  int l = threadIdx.x;
  int cl = l & 15, kg = l >> 4;
  const unsigned short* base = qkv + (size_t)(b * S_) * 3072 + hh * 64;

  {
    const unsigned short* vp = base + 2048 + l;
#pragma unroll 4
    for (int k = 0; k < S_; ++k)
      vT[l][k] = vp[(size_t)k * 3072];
#pragma unroll
    for (int k = S_; k < 64; ++k) vT[l][k] = 0;
  }

  bf16x8 qa[4][2], kb[4][2];
#pragma unroll
  for (int mi = 0; mi < 4; ++mi) {
    int row = mi * 16 + cl;
    bool ok = (row < S_);
    const unsigned short* qp = base + (size_t)row * 3072 + kg * 8;
#pragma unroll
    for (int ks = 0; ks < 2; ++ks) {
      bf16x8 z = {};
      qa[mi][ks] = ok ? *reinterpret_cast<const bf16x8*>(qp + ks * 32) : z;
      kb[mi][ks] = ok ? *reinterpret_cast<const bf16x8*>(qp + 1024 + ks * 32) : z;
    }
  }

  f32x4 acc[4][4] = {};
#pragma unroll
  for (int ks = 0; ks < 2; ++ks)
#pragma unroll
    for (int mi = 0; mi < 4; ++mi)
#pragma unroll
      for (int ci = 0; ci < 4; ++ci)
        acc[mi][ci] = __builtin_amdgcn_mfma_f32_16x16x32_bf16(qa[mi][ks], kb[ci][ks], acc[mi][ci], 0, 0, 0);

  int vld[4];
#pragma unroll
  for (int ci = 0; ci < 4; ++ci) {
    int col = ci * 16 + cl;
    vld[ci] = (col < S_) ? mask[b * S_ + col] : 0;
  }
#pragma unroll
  for (int mi = 0; mi < 4; ++mi)
#pragma unroll
    for (int ci = 0; ci < 4; ++ci)
#pragma unroll
      for (int j = 0; j < 4; ++j)
        sc[mi * 16 + kg * 4 + j][ci * 16 + cl] = vld[ci] ? acc[mi][ci][j] * SCALE_ : -1e9f;

  __syncthreads();

  if (l < S_) {
    float v0 = -3e38f, v1 = -3e38f, v2 = -3e38f, v3 = -3e38f, v4 = -3e38f;
    const float4* rp = reinterpret_cast<const float4*>(&sc[l][0]);
#pragma unroll
    for (int c4 = 0; c4 < 13; ++c4) {
      float4 x = rp[c4];
      float xs[4] = { x.x, x.y, x.z, x.w };
#pragma unroll
      for (int u = 0; u < 4; ++u) {
        float xv = xs[u];
        if      (xv > v0) { v4 = v3; v3 = v2; v2 = v1; v1 = v0; v0 = xv; }
        else if (xv > v1) { v4 = v3; v3 = v2; v2 = v1; v1 = xv; }
        else if (xv > v2) { v4 = v3; v3 = v2; v2 = xv; }
        else if (xv > v3) { v4 = v3; v3 = xv; }
        else if (xv > v4) { v4 = xv; }
      }
    }
    float thr = v4;
    float m = fmaxf(v0, 0.f);
    float denom = 0.f;
    for (int c = 0; c < S_; ++c) {
      float xv = sc[l][c];
      float sp = (xv >= thr) ? xv : 0.f;
      float e = __expf(sp - m);
      denom += e;
      unsigned short hi = f2b(e);
      ph[l][c] = hi;
      plo[l][c] = f2b(e - b2f(hi));
    }
#pragma unroll
    for (int c = S_; c < 64; ++c) { ph[l][c] = 0; plo[l][c] = 0; }
    dnm[l] = 1.f / denom;
  }
  __syncthreads();

  f32x4 o[4][4] = {};
#pragma unroll
  for (int ks = 0; ks < 2; ++ks) {
    bf16x8 vf[4];
#pragma unroll
    for (int di = 0; di < 4; ++di)
      vf[di] = *reinterpret_cast<const bf16x8*>(&vT[di * 16 + cl][ks * 32 + kg * 8]);
#pragma unroll
    for (int mi = 0; mi < 4; ++mi) {
      bf16x8 ahi = *reinterpret_cast<const bf16x8*>(&ph[mi * 16 + cl][ks * 32 + kg * 8]);
      bf16x8 alo = *reinterpret_cast<const bf16x8*>(&plo[mi * 16 + cl][ks * 32 + kg * 8]);
#pragma unroll
      for (int di = 0; di < 4; ++di) {
        o[mi][di] = __builtin_amdgcn_mfma_f32_16x16x32_bf16(ahi, vf[di], o[mi][di], 0, 0, 0);
        o[mi][di] = __builtin_amdgcn_mfma_f32_16x16x32_bf16(alo, vf[di], o[mi][di], 0, 0, 0);
      }
    }
  }

#pragma unroll
  for (int mi = 0; mi < 4; ++mi) {
    int row = mi * 16 + kg * 4;
    if (row < S_) {
#pragma unroll
      for (int j = 0; j < 4; ++j) {
        int r = row + j;
        float inv = dnm[r];
        unsigned short* aop = ao + (size_t)(b * S_ + r) * D_ + hh * DK_;
#pragma unroll
        for (int di = 0; di < 4; ++di)
          aop[di * 16 + cl] = f2b(o[mi][di][j] * inv);
      }
    }
  }
}

// ---------------------------------------------------------------------------
// h = LayerNorm(h + r); r is bf16; writes fp32 h and bf16 hb. Vectorized.
// ---------------------------------------------------------------------------
__global__ __launch_bounds__(256) void k_add_ln(float* __restrict__ h,
    const unsigned short* __restrict__ r, const float* __restrict__ g,
    const float* __restrict__ bb, unsigned short* __restrict__ hb)
{
  int row = blockIdx.x;
  size_t base = (size_t)row * D_;
  int t = threadIdx.x;
  float4 hv = *reinterpret_cast<const float4*>(h + base + t * 4);
  ushortx4 rv = *reinterpret_cast<const ushortx4*>(r + base + t * 4);
  float xs[4] = { hv.x + b2f(rv[0]), hv.y + b2f(rv[1]),
                  hv.z + b2f(rv[2]), hv.w + b2f(rv[3]) };
  float s1 = xs[0] + xs[1] + xs[2] + xs[3];
  float s2 = xs[0] * xs[0] + xs[1] * xs[1] + xs[2] * xs[2] + xs[3] * xs[3];
#pragma unroll
  for (int off = 32; off; off >>= 1) {
    s1 += __shfl_down(s1, off);
    s2 += __shfl_down(s2, off);
  }
  __shared__ float red[8];
  int lane = t & 63, wid = t >> 6;
  if (lane == 0) { red[wid] = s1; red[4 + wid] = s2; }
  __syncthreads();
  if (t == 0) {
    red[0] = red[0] + red[1] + red[2] + red[3];
    red[4] = red[4] + red[5] + red[6] + red[7];
  }
  __syncthreads();
  float mean = red[0] / (float)D_;
  float var  = red[4] / (float)D_ - mean * mean;
  float inv  = rsqrtf(var + EPS_);
  float4 gv = *reinterpret_cast<const float4*>(g + t * 4);
  float4 bv = *reinterpret_cast<const float4*>(bb + t * 4);
  float4 ov;
  ov.x = (xs[0] - mean) * inv * gv.x + bv.x;
  ov.y = (xs[1] - mean) * inv * gv.y + bv.y;
  ov.z = (xs[2] - mean) * inv * gv.z + bv.z;
  ov.w = (xs[3] - mean) * inv * gv.w + bv.w;
  *reinterpret_cast<float4*>(h + base + t * 4) = ov;
  ushortx4 ob = { f2b(ov.x), f2b(ov.y), f2b(ov.z), f2b(ov.w) };
  *reinterpret_cast<ushortx4*>(hb + base + t * 4) = ob;
}

// ---------------------------------------------------------------------------
__global__ __launch_bounds__(256) void k_final(const float* __restrict__ h,
    const float* __restrict__ Wout, const float* __restrict__ bout,
    float* __restrict__ y)
{
  int b = blockIdx.x;
  const float* hr = h + (size_t)(b * S_ + (S_ - 1)) * D_;
  int t = threadIdx.x;
  float p0 = 0.f, p1 = 0.f, p2 = 0.f;
  for (int d = t; d < D_; d += 256) {
    float xv = hr[d];
    p0 += xv * Wout[d];
    p1 += xv * Wout[D_ + d];
    p2 += xv * Wout[2 * D_ + d];
  }
#pragma unroll
  for (int off = 32; off; off >>= 1) {
    p0 += __shfl_down(p0, off);
    p1 += __shfl_down(p1, off);
    p2 += __shfl_down(p2, off);
  }
  __shared__ float red[12];
  int lane = t & 63, wid = t >> 6;
  if (lane == 0) { red[wid] = p0; red[4 + wid] = p1; red[8 + wid] = p2; }
  __syncthreads();
  if (t == 0) {
    y[b * 3 + 0] = red[0] + red[1] + red[2]  + red[3]  + bout[0];
    y[b * 3 + 1] = red[4] + red[5] + red[6]  + red[7]  + bout[1];
    y[b * 3 + 2] = red[8] + red[9] + red[10] + red[11] + bout[2];
  }
}

// ---------------------------------------------------------------------------
extern "C" void kernel_launch(void* const* d_in, const int* in_sizes, int n_in,
                              void* d_out, int out_size, void* d_ws, size_t ws_size,
                              hipStream_t stream)
{
  const int*   x    = (const int*)d_in[0];
  const float* aemb = (const float*)d_in[1];
  const float* sept = (const float*)d_in[2];
  const float* bng  = (const float*)d_in[3];
  const float* bnb  = (const float*)d_in[4];
  const float* Wq = (const float*)d_in[5];  const float* bq = (const float*)d_in[6];
  const float* Wk = (const float*)d_in[7];  const float* bk = (const float*)d_in[8];
  const float* Wv = (const float*)d_in[9];  const float* bv = (const float*)d_in[10];
  const float* Wo = (const float*)d_in[11]; const float* bo = (const float*)d_in[12];
  const float* W1 = (const float*)d_in[13]; const float* b1 = (const float*)d_in[14];
  const float* W2 = (const float*)d_in[15]; const float* b2 = (const float*)d_in[16];
  const float* ln1g = (const float*)d_in[17]; const float* ln1b = (const float*)d_in[18];
  const float* ln2g = (const float*)d_in[19]; const float* ln2b = (const float*)d_in[20];
  const float* Wout = (const float*)d_in[21]; const float* bout = (const float*)d_in[22];
  float* out = (float*)d_out;

  float* ws = (float*)d_ws;
  const size_t TD = (size_t)T_ * D_;
  const size_t DD = (size_t)D_ * D_;
  const size_t DF = (size_t)DFF_ * D_;
  const size_t WPL = 4 * DD + 2 * DF;                               // ushorts/layer
  float* h   = ws;                                                  // TD f32
  unsigned short* tmpb = (unsigned short*)(ws + TD);                // TD bf16
  unsigned short* hb   = (unsigned short*)(ws + 2 * TD);            // TD bf16
  unsigned short* qkvb = (unsigned short*)(ws + 2 * TD + TD / 2);   // 3TD bf16
  unsigned short* aob  = (unsigned short*)(ws + 4 * TD);            // TD bf16
  unsigned short* ffb  = (unsigned short*)(ws + 4 * TD + TD / 2);   // 4TD bf16
  float* bqkv  = ws + 6 * TD + TD / 2;                              // L*3072 f32
  float* stats = bqkv + L_ * 3072;
  float* part  = stats + 2 * S_;
  int*   mask  = (int*)(part + 2 * S_ * B_);
  size_t usedB = ((char*)(mask + T_) - (char*)ws + 255) & ~(size_t)255;
  unsigned short* wbuf = (unsigned short*)((char*)ws + usedB);
  const int all8 = (ws_size >= usedB + 8 * WPL * sizeof(unsigned short)) ? 1 : 0;

  k_embed<<<T_, 256, 0, stream>>>(x, aemb, sept, h, part, mask);
  k_bn_reduce<<<S_, 128, 0, stream>>>(part, stats);
  k_bn_apply<<<T_, 256, 0, stream>>>(h, stats, bng, bnb, hb);
  k_bcat<<<(L_ * 3072) / 256, 256, 0, stream>>>(bq, bk, bv, bqkv);
  if (all8)
    k_wconv6<<<dim3(512, 6, 8), 256, 0, stream>>>(Wq, Wk, Wv, Wo, W1, W2, wbuf);

  for (int l = 0; l < L_; ++l) {
    unsigned short* wl = all8 ? (wbuf + (size_t)l * WPL) : wbuf;
    if (!all8)
      k_wconv6<<<dim3(512, 6, 1), 256, 0, stream>>>(Wq + l * DD, Wk + l * DD,
          Wv + l * DD, Wo + l * DD, W1 + l * DF, W2 + l * DF, wbuf);
    // QKV: M=6656 (26 Mtiles of 256), N=3072 (24 Ntiles of 128), K=1024
    k_gemm8<0, 1><<<26 * 24, 512, 0, stream>>>(hb, wl, bqkv + l * 3072,
        qkvb, 26, 24, 1024, 3072);
    k_attn<<<B_ * H_, 64, 0, stream>>>(qkvb, mask, aob);
    // O-proj: N=1024 (8 Ntiles), K=1024 -> bf16 tmpb
    k_gemm8<0, 1><<<26 * 8, 512, 0, stream>>>(aob, wl + 3 * DD, bo + l * D_,
        tmpb, 26, 8, 1024, 1024);
    k_add_ln<<<T_, 256, 0, stream>>>(h, tmpb, ln1g + l * D_, ln1b + l * D_, hb);
    // FFN1: N=4096 (32 Ntiles), K=1024, relu
    k_gemm8<1, 1><<<26 * 32, 512, 0, stream>>>(hb, wl + 4 * DD, b1 + l * DFF_,
        ffb, 26, 32, 1024, 4096);
    // FFN2: N=1024 (8 Ntiles), K=4096 -> bf16 tmpb
    k_gemm8<0, 1><<<26 * 8, 512, 0, stream>>>(ffb, wl + 4 * DD + DF, b2 + l * D_,
        tmpb, 26, 8, 4096, 1024);
    k_add_ln<<<T_, 256, 0, stream>>>(h, tmpb, ln2g + l * D_, ln2b + l * D_, hb);
  }
  k_final<<<B_, 256, 0, stream>>>(h, Wout, bout, out);
}

// Round 14
// 2371.623 us; speedup vs baseline: 6.0240x; 1.1238x over previous
//
#include <hip/hip_runtime.h>
#include <cstddef>
#include <cstdint>

#define B_    128
#define S_    52
#define D_    1024
#define H_    16
#define L_    8
#define DFF_  4096
#define DK_   64
#define T_    (B_*S_)
#define EPS_  1e-5f
#define SCALE_ 0.125f

typedef unsigned short ushortx4 __attribute__((ext_vector_type(4)));
typedef unsigned short ushortx8 __attribute__((ext_vector_type(8)));
typedef short  bf16x8 __attribute__((ext_vector_type(8)));
typedef float  f32x4  __attribute__((ext_vector_type(4)));

__device__ __forceinline__ unsigned short f2b(float f) {
  unsigned int u = __builtin_bit_cast(unsigned int, f);
  u = u + 0x7fffu + ((u >> 16) & 1u);
  return (unsigned short)(u >> 16);
}
__device__ __forceinline__ float b2f(unsigned short b) {
  unsigned int u = ((unsigned int)b) << 16;
  return __builtin_bit_cast(float, u);
}
__device__ __forceinline__ void gload16(const void* g, void* l) {
  __builtin_amdgcn_global_load_lds((const __attribute__((address_space(1))) unsigned int*)g,
      (__attribute__((address_space(3))) unsigned int*)l, 16, 0, 0);
}

// ---------------------------------------------------------------------------
// Embedding + BN partial stats
// ---------------------------------------------------------------------------
__global__ __launch_bounds__(256) void k_embed(const int* __restrict__ x,
    const float* __restrict__ aemb, const float* __restrict__ sept,
    float* __restrict__ h, float* __restrict__ part, int* __restrict__ mask)
{
  int row = blockIdx.x;
  int b = row / S_;
  int s = row - b * S_;
  const int* xr = x + (size_t)row * 3;
  int x0 = xr[0], x1 = xr[1], x2 = xr[2];
  bool issep = (x0 == 100) && (x1 == 0) && (x2 == 2);
  bool ispad = (x0 == 100) && (x1 == 0) && (x2 == 0);
  int t = threadIdx.x;
  if (t == 0) mask[row] = ispad ? 0 : 1;
  const float* src = issep ? sept : (aemb + (size_t)x2 * D_);
  size_t base = (size_t)row * D_;
  float4 v = *reinterpret_cast<const float4*>(src + t * 4);
  *reinterpret_cast<float4*>(h + base + t * 4) = v;
  float s1 = v.x + v.y + v.z + v.w;
  float s2 = v.x * v.x + v.y * v.y + v.z * v.z + v.w * v.w;
#pragma unroll
  for (int off = 32; off; off >>= 1) {
    s1 += __shfl_down(s1, off);
    s2 += __shfl_down(s2, off);
  }
  __shared__ float red[8];
  int lane = t & 63, wid = t >> 6;
  if (lane == 0) { red[wid] = s1; red[4 + wid] = s2; }
  __syncthreads();
  if (t == 0) {
    part[(size_t)s * B_ + b]        = red[0] + red[1] + red[2] + red[3];
    part[(size_t)(S_ + s) * B_ + b] = red[4] + red[5] + red[6] + red[7];
  }
}

__global__ __launch_bounds__(128) void k_bn_reduce(const float* __restrict__ part,
                                                   float* __restrict__ stats)
{
  int s = blockIdx.x;
  int t = threadIdx.x;
  float s1 = part[(size_t)s * B_ + t];
  float s2 = part[(size_t)(S_ + s) * B_ + t];
#pragma unroll
  for (int off = 32; off; off >>= 1) {
    s1 += __shfl_down(s1, off);
    s2 += __shfl_down(s2, off);
  }
  __shared__ float red[4];
  int lane = t & 63, wid = t >> 6;
  if (lane == 0) { red[wid] = s1; red[2 + wid] = s2; }
  __syncthreads();
  if (t == 0) {
    stats[s]      = red[0] + red[1];
    stats[S_ + s] = red[2] + red[3];
  }
}

__global__ __launch_bounds__(256) void k_bn_apply(float* __restrict__ h,
    const float* __restrict__ stats, const float* __restrict__ g,
    const float* __restrict__ bb, unsigned short* __restrict__ hb)
{
  int row = blockIdx.x;
  int s = row % S_;
  const float cnt = (float)(B_ * D_);
  float mu  = stats[s] / cnt;
  float var = stats[S_ + s] / cnt - mu * mu;
  float sc  = rsqrtf(var + EPS_) * g[s];
  float off = bb[s] - mu * sc;
  size_t base = (size_t)row * D_;
  int t = threadIdx.x;
  float4 v = *reinterpret_cast<const float4*>(h + base + t * 4);
  v.x = v.x * sc + off; v.y = v.y * sc + off;
  v.z = v.z * sc + off; v.w = v.w * sc + off;
  *reinterpret_cast<float4*>(h + base + t * 4) = v;
  ushortx4 o = { f2b(v.x), f2b(v.y), f2b(v.z), f2b(v.w) };
  *reinterpret_cast<ushortx4*>(hb + base + t * 4) = o;
}

// divide-free vectorized weight conversion: blockIdx.y = segment, .z = layer
__global__ __launch_bounds__(256) void k_wconv6(
    const float* __restrict__ Wq, const float* __restrict__ Wk,
    const float* __restrict__ Wv, const float* __restrict__ Wo,
    const float* __restrict__ W1, const float* __restrict__ W2,
    unsigned short* __restrict__ out)
{
  const size_t DD = (size_t)D_ * D_, DF = (size_t)DFF_ * D_;
  const size_t WPL = 4 * DD + 2 * DF;
  int s = blockIdx.y, l = blockIdx.z;
  const float* src; size_t segsz, dstoff;
  switch (s) {
    case 0:  src = Wq + (size_t)l * DD; segsz = DD; dstoff = 0; break;
    case 1:  src = Wk + (size_t)l * DD; segsz = DD; dstoff = DD; break;
    case 2:  src = Wv + (size_t)l * DD; segsz = DD; dstoff = 2 * DD; break;
    case 3:  src = Wo + (size_t)l * DD; segsz = DD; dstoff = 3 * DD; break;
    case 4:  src = W1 + (size_t)l * DF; segsz = DF; dstoff = 4 * DD; break;
    default: src = W2 + (size_t)l * DF; segsz = DF; dstoff = 4 * DD + DF; break;
  }
  unsigned short* dst = out + (size_t)l * WPL + dstoff;
  size_t stride = (size_t)gridDim.x * 256 * 8;
  for (size_t i = ((size_t)blockIdx.x * 256 + threadIdx.x) * 8; i < segsz; i += stride) {
    float4 v0 = *reinterpret_cast<const float4*>(src + i);
    float4 v1 = *reinterpret_cast<const float4*>(src + i + 4);
    ushortx8 o = { f2b(v0.x), f2b(v0.y), f2b(v0.z), f2b(v0.w),
                   f2b(v1.x), f2b(v1.y), f2b(v1.z), f2b(v1.w) };
    *reinterpret_cast<ushortx8*>(dst + i) = o;
  }
}

// concat per-layer qkv biases -> bqkv_all[L][3072]
__global__ __launch_bounds__(256) void k_bcat(const float* __restrict__ bq,
    const float* __restrict__ bk, const float* __restrict__ bv,
    float* __restrict__ out)
{
  int i = blockIdx.x * 256 + threadIdx.x;
  int l = i / 3072, j = i - l * 3072;
  float v = (j < D_) ? bq[l * D_ + j] : (j < 2 * D_) ? bk[l * D_ + j - D_]
                                                     : bv[l * D_ + j - 2 * D_];
  out[i] = v;
}

// ---------------------------------------------------------------------------
// Pipelined bf16 MFMA GEMM (R11 proven best): C = A @ Wt^T + bias
// BM=256, BN=128, BK=32, 8 waves (4M x 2N), wave-tile 64x64.
// 3 LDS buffers x 24KB = 72KB -> 2 blocks/CU. Depth-2 prefetch, COUNTED
// vmcnt(3) (R13 showed depth-1 vmcnt(0)-drain costs ~10%). Do NOT raise the
// 2nd __launch_bounds__ arg above 4 (R12: (512,6) -> VGPR cap 40 -> spills).
// 64B-row swizzle sigma(row)=(row>>1)&3 on source AND ds_read (0 conflicts).
// 8x8 supertile under XCD swizzle.
// ---------------------------------------------------------------------------
template<int RELU, int OUTBF16>
__global__ __launch_bounds__(512, 4) void k_gemm8(
    const unsigned short* __restrict__ A, const unsigned short* __restrict__ Wt,
    const float* __restrict__ bias, void* __restrict__ C,
    int Mtiles, int Ntiles, int K, int ldc)
{
  __shared__ unsigned short lds[3 * 12288];   // 72 KB
  const int tid = threadIdx.x;
  const int w = tid >> 6, l = tid & 63;

  const int nwg = Mtiles * Ntiles;
  int id = blockIdx.x;
  int swz = (id & 7) * (nwg >> 3) + (id >> 3);
  const int stripe = swz / (Ntiles << 3);
  const int r = swz - stripe * (Ntiles << 3);
  int hg = Mtiles - (stripe << 3); if (hg > 8) hg = 8;
  const int c = r / (hg << 3);
  const int q = r - c * (hg << 3);
  const int bym = (stripe << 3) + (q >> 3);
  const int bxn = (c << 3) + (q & 7);
  const int bm = bym * 256, bn = bxn * 128;

  const int colsw = 16 * ((l & 3) ^ ((l >> 3) & 3));
  const char* gA = (const char*)A + ((size_t)(bm + w * 32 + (l >> 2)) * K) * 2 + colsw;
  const char* gB = (const char*)Wt + ((size_t)(bn + w * 16 + (l >> 2)) * K) * 2 + colsw;
  const size_t r16 = (size_t)16 * K * 2;
  unsigned short* lA = lds + w * 1024;
  unsigned short* lB = lds + 8192 + w * 512;

#define STAGE(tt, bb) do {                          \
    size_t ko_ = (size_t)(tt) * 64;                 \
    unsigned short* la_ = lA + (bb) * 12288;        \
    unsigned short* lb_ = lB + (bb) * 12288;        \
    gload16(gA + ko_,       la_);                   \
    gload16(gA + ko_ + r16, la_ + 512);             \
    gload16(gB + ko_,       lb_);                   \
  } while (0)

  const int fr = l & 15, kg = l >> 4;
  const int wr = w >> 1, wc = w & 1;
  const int xk = 16 * (kg ^ ((fr >> 1) & 3));
  const int aOff = (wr * 64 + fr) * 64 + xk;
  const int bOff = 16384 + (wc * 64 + fr) * 64 + xk;

  f32x4 acc[4][4] = {};
  const int NT = K >> 5;

  STAGE(0, 0);
  STAGE(1, 1);
  int cur = 0;
  for (int t = 0; t < NT; ++t) {
    if (t + 1 < NT) { asm volatile("s_waitcnt vmcnt(3)" ::: "memory"); }
    else            { asm volatile("s_waitcnt vmcnt(0)" ::: "memory"); }
    __builtin_amdgcn_sched_barrier(0);
    __builtin_amdgcn_s_barrier();
    __builtin_amdgcn_sched_barrier(0);
    if (t + 2 < NT) {
      int nb = cur + 2; if (nb >= 3) nb -= 3;
      STAGE(t + 2, nb);
    }
    const char* bp = (const char*)lds + cur * 24576;
    bf16x8 af[4], bfv[4];
#pragma unroll
    for (int mf = 0; mf < 4; ++mf)
      af[mf] = *(const bf16x8*)(bp + aOff + mf * 1024);
#pragma unroll
    for (int nf = 0; nf < 4; ++nf)
      bfv[nf] = *(const bf16x8*)(bp + bOff + nf * 1024);
    asm volatile("s_waitcnt lgkmcnt(0)" ::: "memory");
    __builtin_amdgcn_sched_barrier(0);
    __builtin_amdgcn_s_setprio(1);
#pragma unroll
    for (int mf = 0; mf < 4; ++mf)
#pragma unroll
      for (int nf = 0; nf < 4; ++nf)
        acc[mf][nf] = __builtin_amdgcn_mfma_f32_16x16x32_bf16(af[mf], bfv[nf], acc[mf][nf], 0, 0, 0);
    __builtin_amdgcn_s_setprio(0);
    __builtin_amdgcn_sched_barrier(0);
    cur = (cur == 2) ? 0 : cur + 1;
  }
#undef STAGE

#pragma unroll
  for (int nf = 0; nf < 4; ++nf) {
    int col = bn + wc * 64 + nf * 16 + fr;
    float bv = bias[col];
#pragma unroll
    for (int mf = 0; mf < 4; ++mf) {
      int row0 = bm + wr * 64 + mf * 16 + kg * 4;
#pragma unroll
      for (int j = 0; j < 4; ++j) {
        float v = acc[mf][nf][j] + bv;
        if (RELU) v = fmaxf(v, 0.f);
        if (OUTBF16)
          ((unsigned short*)C)[(size_t)(row0 + j) * ldc + col] = f2b(v);
        else
          ((float*)C)[(size_t)(row0 + j) * ldc + col] = v;
      }
    }
  }
}

// ---------------------------------------------------------------------------
// 128x128-tile clone of the SAME 3-buffer counted-vmcnt pipeline, for the
// skinny-N GEMMs (O-proj, FFN2: Ntiles=8 at BN=128). 4 waves (2M x 2N),
// 256 threads, 3 x 16KB LDS = 48KB -> 3 blocks/CU, 416 blocks (vs 208 big
// ones on 512 slots). Stage = 4 gload16/thread (A half0/half1, B half0/half1;
// dest w*512 + l*8 ushorts = contiguous per wave, verified). vmcnt(4) =
// one stage's worth outstanding. Same sigma swizzle both sides.
// ---------------------------------------------------------------------------
template<int RELU, int OUTBF16>
__global__ __launch_bounds__(256, 4) void k_gemm4(
    const unsigned short* __restrict__ A, const unsigned short* __restrict__ Wt,
    const float* __restrict__ bias, void* __restrict__ C,
    int Mtiles, int Ntiles, int K, int ldc)
{
  __shared__ unsigned short lds[3 * 8192];   // 48 KB
  const int tid = threadIdx.x;
  const int w = tid >> 6, l = tid & 63;

  const int nwg = Mtiles * Ntiles;
  int id = blockIdx.x;
  int swz = (id & 7) * (nwg >> 3) + (id >> 3);
  const int stripe = swz / (Ntiles << 3);
  const int r = swz - stripe * (Ntiles << 3);
  int hg = Mtiles - (stripe << 3); if (hg > 8) hg = 8;
  const int c = r / (hg << 3);
  const int q = r - c * (hg << 3);
  const int bym = (stripe << 3) + (q >> 3);
  const int bxn = (c << 3) + (q & 7);
  const int bm = bym * 128, bn = bxn * 128;

  // staging: thread covers rows (tid>>2) and (tid>>2)+64 of A and B, chunk tid&3
  // sigma(row) = (row>>1)&3 = (tid>>3)&3 for both halves (64 % 4 == 0)
  const int colsw = 16 * ((tid & 3) ^ ((tid >> 3) & 3));
  const char* gA = (const char*)A + ((size_t)(bm + (tid >> 2)) * K) * 2 + colsw;
  const char* gB = (const char*)Wt + ((size_t)(bn + (tid >> 2)) * K) * 2 + colsw;
  const size_t r64 = (size_t)64 * K * 2;
  unsigned short* lA = lds + w * 512;          // + buf*8192 (+2048 for half 1)
  unsigned short* lB = lds + 4096 + w * 512;

#define STAGE4(tt, bb) do {                         \
    size_t ko_ = (size_t)(tt) * 64;                 \
    unsigned short* la_ = lA + (bb) * 8192;         \
    unsigned short* lb_ = lB + (bb) * 8192;         \
    gload16(gA + ko_,       la_);                   \
    gload16(gA + ko_ + r64, la_ + 2048);            \
    gload16(gB + ko_,       lb_);                   \
    gload16(gB + ko_ + r64, lb_ + 2048);            \
  } while (0)

  const int fr = l & 15, kg = l >> 4;
  const int wr = w >> 1, wc = w & 1;
  const int xk = 16 * (kg ^ ((fr >> 1) & 3));
  const int aOff = (wr * 64 + fr) * 64 + xk;          // bytes; + mf*1024
  const int bOff = 8192 + (wc * 64 + fr) * 64 + xk;   // bytes; + nf*1024

  f32x4 acc[4][4] = {};
  const int NT = K >> 5;

  STAGE4(0, 0);
  STAGE4(1, 1);
  int cur = 0;
  for (int t = 0; t < NT; ++t) {
    if (t + 1 < NT) { asm volatile("s_waitcnt vmcnt(4)" ::: "memory"); }
    else            { asm volatile("s_waitcnt vmcnt(0)" ::: "memory"); }
    __builtin_amdgcn_sched_barrier(0);
    __builtin_amdgcn_s_barrier();
    __builtin_amdgcn_sched_barrier(0);
    if (t + 2 < NT) {
      int nb = cur + 2; if (nb >= 3) nb -= 3;
      STAGE4(t + 2, nb);
    }
    const char* bp = (const char*)lds + cur * 16384;
    bf16x8 af[4], bfv[4];
#pragma unroll
    for (int mf = 0; mf < 4; ++mf)
      af[mf] = *(const bf16x8*)(bp + aOff + mf * 1024);
#pragma unroll
    for (int nf = 0; nf < 4; ++nf)
      bfv[nf] = *(const bf16x8*)(bp + bOff + nf * 1024);
    asm volatile("s_waitcnt lgkmcnt(0)" ::: "memory");
    __builtin_amdgcn_sched_barrier(0);
    __builtin_amdgcn_s_setprio(1);
#pragma unroll
    for (int mf = 0; mf < 4; ++mf)
#pragma unroll
      for (int nf = 0; nf < 4; ++nf)
        acc[mf][nf] = __builtin_amdgcn_mfma_f32_16x16x32_bf16(af[mf], bfv[nf], acc[mf][nf], 0, 0, 0);
    __builtin_amdgcn_s_setprio(0);
    __builtin_amdgcn_sched_barrier(0);
    cur = (cur == 2) ? 0 : cur + 1;
  }
#undef STAGE4

#pragma unroll
  for (int nf = 0; nf < 4; ++nf) {
    int col = bn + wc * 64 + nf * 16 + fr;
    float bv = bias[col];
#pragma unroll
    for (int mf = 0; mf < 4; ++mf) {
      int row0 = bm + wr * 64 + mf * 16 + kg * 4;
#pragma unroll
      for (int j = 0; j < 4; ++j) {
        float v = acc[mf][nf][j] + bv;
        if (RELU) v = fmaxf(v, 0.f);
        if (OUTBF16)
          ((unsigned short*)C)[(size_t)(row0 + j) * ldc + col] = f2b(v);
        else
          ((float*)C)[(size_t)(row0 + j) * ldc + col] = v;
      }
    }
  }
}

// ---------------------------------------------------------------------------
// MFMA sparse attention: one wave per (b, head).
// ---------------------------------------------------------------------------
__global__ __launch_bounds__(64) void k_attn(const unsigned short* __restrict__ qkv,
    const int* __restrict__ mask, unsigned short* __restrict__ ao)
{
  __shared__ float sc[64][68];
  __shared__ unsigned short ph[64][68];
  __shared__ unsigned short plo[64][68];
  __shared__ unsigned short vT[64][68];
  __shared__ float dnm[64];

  int blk = blockIdx.x;
  int b = blk >> 4, hh = blk & 15;
  int l = threadIdx.x;
  int cl = l & 15, kg = l >> 4;
  const unsigned short* base = qkv + (size_t)(b * S_) * 3072 + hh * 64;

  {
    const unsigned short* vp = base + 2048 + l;
#pragma unroll 4
    for (int k = 0; k < S_; ++k)
      vT[l][k] = vp[(size_t)k * 3072];
#pragma unroll
    for (int k = S_; k < 64; ++k) vT[l][k] = 0;
  }

  bf16x8 qa[4][2], kb[4][2];
#pragma unroll
  for (int mi = 0; mi < 4; ++mi) {
    int row = mi * 16 + cl;
    bool ok = (row < S_);
    const unsigned short* qp = base + (size_t)row * 3072 + kg * 8;
#pragma unroll
    for (int ks = 0; ks < 2; ++ks) {
      bf16x8 z = {};
      qa[mi][ks] = ok ? *reinterpret_cast<const bf16x8*>(qp + ks * 32) : z;
      kb[mi][ks] = ok ? *reinterpret_cast<const bf16x8*>(qp + 1024 + ks * 32) : z;
    }
  }

  f32x4 acc[4][4] = {};
#pragma unroll
  for (int ks = 0; ks < 2; ++ks)
#pragma unroll
    for (int mi = 0; mi < 4; ++mi)
#pragma unroll
      for (int ci = 0; ci < 4; ++ci)
        acc[mi][ci] = __builtin_amdgcn_mfma_f32_16x16x32_bf16(qa[mi][ks], kb[ci][ks], acc[mi][ci], 0, 0, 0);

  int vld[4];
#pragma unroll
  for (int ci = 0; ci < 4; ++ci) {
    int col = ci * 16 + cl;
    vld[ci] = (col < S_) ? mask[b * S_ + col] : 0;
  }
#pragma unroll
  for (int mi = 0; mi < 4; ++mi)
#pragma unroll
    for (int ci = 0; ci < 4; ++ci)
#pragma unroll
      for (int j = 0; j < 4; ++j)
        sc[mi * 16 + kg * 4 + j][ci * 16 + cl] = vld[ci] ? acc[mi][ci][j] * SCALE_ : -1e9f;

  __syncthreads();

  if (l < S_) {
    float v0 = -3e38f, v1 = -3e38f, v2 = -3e38f, v3 = -3e38f, v4 = -3e38f;
    const float4* rp = reinterpret_cast<const float4*>(&sc[l][0]);
#pragma unroll
    for (int c4 = 0; c4 < 13; ++c4) {
      float4 x = rp[c4];
      float xs[4] = { x.x, x.y, x.z, x.w };
#pragma unroll
      for (int u = 0; u < 4; ++u) {
        float xv = xs[u];
        if      (xv > v0) { v4 = v3; v3 = v2; v2 = v1; v1 = v0; v0 = xv; }
        else if (xv > v1) { v4 = v3; v3 = v2; v2 = v1; v1 = xv; }
        else if (xv > v2) { v4 = v3; v3 = v2; v2 = xv; }
        else if (xv > v3) { v4 = v3; v3 = xv; }
        else if (xv > v4) { v4 = xv; }
      }
    }
    float thr = v4;
    float m = fmaxf(v0, 0.f);
    float denom = 0.f;
    for (int c = 0; c < S_; ++c) {
      float xv = sc[l][c];
      float sp = (xv >= thr) ? xv : 0.f;
      float e = __expf(sp - m);
      denom += e;
      unsigned short hi = f2b(e);
      ph[l][c] = hi;
      plo[l][c] = f2b(e - b2f(hi));
    }
#pragma unroll
    for (int c = S_; c < 64; ++c) { ph[l][c] = 0; plo[l][c] = 0; }
    dnm[l] = 1.f / denom;
  }
  __syncthreads();

  f32x4 o[4][4] = {};
#pragma unroll
  for (int ks = 0; ks < 2; ++ks) {
    bf16x8 vf[4];
#pragma unroll
    for (int di = 0; di < 4; ++di)
      vf[di] = *reinterpret_cast<const bf16x8*>(&vT[di * 16 + cl][ks * 32 + kg * 8]);
#pragma unroll
    for (int mi = 0; mi < 4; ++mi) {
      bf16x8 ahi = *reinterpret_cast<const bf16x8*>(&ph[mi * 16 + cl][ks * 32 + kg * 8]);
      bf16x8 alo = *reinterpret_cast<const bf16x8*>(&plo[mi * 16 + cl][ks * 32 + kg * 8]);
#pragma unroll
      for (int di = 0; di < 4; ++di) {
        o[mi][di] = __builtin_amdgcn_mfma_f32_16x16x32_bf16(ahi, vf[di], o[mi][di], 0, 0, 0);
        o[mi][di] = __builtin_amdgcn_mfma_f32_16x16x32_bf16(alo, vf[di], o[mi][di], 0, 0, 0);
      }
    }
  }

#pragma unroll
  for (int mi = 0; mi < 4; ++mi) {
    int row = mi * 16 + kg * 4;
    if (row < S_) {
#pragma unroll
      for (int j = 0; j < 4; ++j) {
        int r = row + j;
        float inv = dnm[r];
        unsigned short* aop = ao + (size_t)(b * S_ + r) * D_ + hh * DK_;
#pragma unroll
        for (int di = 0; di < 4; ++di)
          aop[di * 16 + cl] = f2b(o[mi][di][j] * inv);
      }
    }
  }
}

// ---------------------------------------------------------------------------
// h = LayerNorm(h + r); r is bf16; writes fp32 h and bf16 hb. Vectorized.
// ---------------------------------------------------------------------------
__global__ __launch_bounds__(256) void k_add_ln(float* __restrict__ h,
    const unsigned short* __restrict__ r, const float* __restrict__ g,
    const float* __restrict__ bb, unsigned short* __restrict__ hb)
{
  int row = blockIdx.x;
  size_t base = (size_t)row * D_;
  int t = threadIdx.x;
  float4 hv = *reinterpret_cast<const float4*>(h + base + t * 4);
  ushortx4 rv = *reinterpret_cast<const ushortx4*>(r + base + t * 4);
  float xs[4] = { hv.x + b2f(rv[0]), hv.y + b2f(rv[1]),
                  hv.z + b2f(rv[2]), hv.w + b2f(rv[3]) };
  float s1 = xs[0] + xs[1] + xs[2] + xs[3];
  float s2 = xs[0] * xs[0] + xs[1] * xs[1] + xs[2] * xs[2] + xs[3] * xs[3];
#pragma unroll
  for (int off = 32; off; off >>= 1) {
    s1 += __shfl_down(s1, off);
    s2 += __shfl_down(s2, off);
  }
  __shared__ float red[8];
  int lane = t & 63, wid = t >> 6;
  if (lane == 0) { red[wid] = s1; red[4 + wid] = s2; }
  __syncthreads();
  if (t == 0) {
    red[0] = red[0] + red[1] + red[2] + red[3];
    red[4] = red[4] + red[5] + red[6] + red[7];
  }
  __syncthreads();
  float mean = red[0] / (float)D_;
  float var  = red[4] / (float)D_ - mean * mean;
  float inv  = rsqrtf(var + EPS_);
  float4 gv = *reinterpret_cast<const float4*>(g + t * 4);
  float4 bv = *reinterpret_cast<const float4*>(bb + t * 4);
  float4 ov;
  ov.x = (xs[0] - mean) * inv * gv.x + bv.x;
  ov.y = (xs[1] - mean) * inv * gv.y + bv.y;
  ov.z = (xs[2] - mean) * inv * gv.z + bv.z;
  ov.w = (xs[3] - mean) * inv * gv.w + bv.w;
  *reinterpret_cast<float4*>(h + base + t * 4) = ov;
  ushortx4 ob = { f2b(ov.x), f2b(ov.y), f2b(ov.z), f2b(ov.w) };
  *reinterpret_cast<ushortx4*>(hb + base + t * 4) = ob;
}

// ---------------------------------------------------------------------------
__global__ __launch_bounds__(256) void k_final(const float* __restrict__ h,
    const float* __restrict__ Wout, const float* __restrict__ bout,
    float* __restrict__ y)
{
  int b = blockIdx.x;
  const float* hr = h + (size_t)(b * S_ + (S_ - 1)) * D_;
  int t = threadIdx.x;
  float p0 = 0.f, p1 = 0.f, p2 = 0.f;
  for (int d = t; d < D_; d += 256) {
    float xv = hr[d];
    p0 += xv * Wout[d];
    p1 += xv * Wout[D_ + d];
    p2 += xv * Wout[2 * D_ + d];
  }
#pragma unroll
  for (int off = 32; off; off >>= 1) {
    p0 += __shfl_down(p0, off);
    p1 += __shfl_down(p1, off);
    p2 += __shfl_down(p2, off);
  }
  __shared__ float red[12];
  int lane = t & 63, wid = t >> 6;
  if (lane == 0) { red[wid] = p0; red[4 + wid] = p1; red[8 + wid] = p2; }
  __syncthreads();
  if (t == 0) {
    y[b * 3 + 0] = red[0] + red[1] + red[2]  + red[3]  + bout[0];
    y[b * 3 + 1] = red[4] + red[5] + red[6]  + red[7]  + bout[1];
    y[b * 3 + 2] = red[8] + red[9] + red[10] + red[11] + bout[2];
  }
}

// ---------------------------------------------------------------------------
extern "C" void kernel_launch(void* const* d_in, const int* in_sizes, int n_in,
                              void* d_out, int out_size, void* d_ws, size_t ws_size,
                              hipStream_t stream)
{
  const int*   x    = (const int*)d_in[0];
  const float* aemb = (const float*)d_in[1];
  const float* sept = (const float*)d_in[2];
  const float* bng  = (const float*)d_in[3];
  const float* bnb  = (const float*)d_in[4];
  const float* Wq = (const float*)d_in[5];  const float* bq = (const float*)d_in[6];
  const float* Wk = (const float*)d_in[7];  const float* bk = (const float*)d_in[8];
  const float* Wv = (const float*)d_in[9];  const float* bv = (const float*)d_in[10];
  const float* Wo = (const float*)d_in[11]; const float* bo = (const float*)d_in[12];
  const float* W1 = (const float*)d_in[13]; const float* b1 = (const float*)d_in[14];
  const float* W2 = (const float*)d_in[15]; const float* b2 = (const float*)d_in[16];
  const float* ln1g = (const float*)d_in[17]; const float* ln1b = (const float*)d_in[18];
  const float* ln2g = (const float*)d_in[19]; const float* ln2b = (const float*)d_in[20];
  const float* Wout = (const float*)d_in[21]; const float* bout = (const float*)d_in[22];
  float* out = (float*)d_out;

  float* ws = (float*)d_ws;
  const size_t TD = (size_t)T_ * D_;
  const size_t DD = (size_t)D_ * D_;
  const size_t DF = (size_t)DFF_ * D_;
  const size_t WPL = 4 * DD + 2 * DF;                               // ushorts/layer
  float* h   = ws;                                                  // TD f32
  unsigned short* tmpb = (unsigned short*)(ws + TD);                // TD bf16
  unsigned short* hb   = (unsigned short*)(ws + 2 * TD);            // TD bf16
  unsigned short* qkvb = (unsigned short*)(ws + 2 * TD + TD / 2);   // 3TD bf16
  unsigned short* aob  = (unsigned short*)(ws + 4 * TD);            // TD bf16
  unsigned short* ffb  = (unsigned short*)(ws + 4 * TD + TD / 2);   // 4TD bf16
  float* bqkv  = ws + 6 * TD + TD / 2;                              // L*3072 f32
  float* stats = bqkv + L_ * 3072;
  float* part  = stats + 2 * S_;
  int*   mask  = (int*)(part + 2 * S_ * B_);
  size_t usedB = ((char*)(mask + T_) - (char*)ws + 255) & ~(size_t)255;
  unsigned short* wbuf = (unsigned short*)((char*)ws + usedB);
  const int all8 = (ws_size >= usedB + 8 * WPL * sizeof(unsigned short)) ? 1 : 0;

  k_embed<<<T_, 256, 0, stream>>>(x, aemb, sept, h, part, mask);
  k_bn_reduce<<<S_, 128, 0, stream>>>(part, stats);
  k_bn_apply<<<T_, 256, 0, stream>>>(h, stats, bng, bnb, hb);
  k_bcat<<<(L_ * 3072) / 256, 256, 0, stream>>>(bq, bk, bv, bqkv);
  if (all8)
    k_wconv6<<<dim3(512, 6, 8), 256, 0, stream>>>(Wq, Wk, Wv, Wo, W1, W2, wbuf);

  for (int l = 0; l < L_; ++l) {
    unsigned short* wl = all8 ? (wbuf + (size_t)l * WPL) : wbuf;
    if (!all8)
      k_wconv6<<<dim3(512, 6, 1), 256, 0, stream>>>(Wq + l * DD, Wk + l * DD,
          Wv + l * DD, Wo + l * DD, W1 + l * DF, W2 + l * DF, wbuf);
    // QKV: M=6656 (26 Mtiles of 256), N=3072 (24 Ntiles of 128), K=1024
    k_gemm8<0, 1><<<26 * 24, 512, 0, stream>>>(hb, wl, bqkv + l * 3072,
        qkvb, 26, 24, 1024, 3072);
    k_attn<<<B_ * H_, 64, 0, stream>>>(qkvb, mask, aob);
    // O-proj: 128-tile variant, 52x8 = 416 blocks -> bf16 tmpb
    k_gemm4<0, 1><<<52 * 8, 256, 0, stream>>>(aob, wl + 3 * DD, bo + l * D_,
        tmpb, 52, 8, 1024, 1024);
    k_add_ln<<<T_, 256, 0, stream>>>(h, tmpb, ln1g + l * D_, ln1b + l * D_, hb);
    // FFN1: N=4096 (32 Ntiles), K=1024, relu
    k_gemm8<1, 1><<<26 * 32, 512, 0, stream>>>(hb, wl + 4 * DD, b1 + l * DFF_,
        ffb, 26, 32, 1024, 4096);
    // FFN2: 128-tile variant, 416 blocks, K=4096 -> bf16 tmpb
    k_gemm4<0, 1><<<52 * 8, 256, 0, stream>>>(ffb, wl + 4 * DD + DF, b2 + l * D_,
        tmpb, 52, 8, 4096, 1024);
    k_add_ln<<<T_, 256, 0, stream>>>(h, tmpb, ln2g + l * D_, ln2b + l * D_, hb);
  }
  k_final<<<B_, 256, 0, stream>>>(h, Wout, bout, out);
}